// Round 8
// baseline (127.119 us; speedup 1.0000x reference)
//
#include <hip/hip_runtime.h>

// ACmix: b=2, C=64 (HEAD=4 x HEAD_DIM=16), (d,w,h)=(8,32,32), L=8192
// Attention view: (H2,W2)=(64,128). Conv view: (8, 1024). K_ATT=7 PAD=3.
//
// R8: 2 dispatches.  attconv fuses attention + depthwise conv:
//   phase A/B = R7 att (512 thr, 2 thr/pixel channel split); att result
//   parked in att_buf LDS (nothing live across re-stage -> no R5 spill).
//   phase C = conv with WAVE-UNIFORM channel ownership (wave w -> channels
//   {2w,2w+1}, one f-group) so wdep stays on the scalar s_load path; lane
//   covers 4 pixels via a 4-row register window.  Single writer of out.

// ---------------------------------------------------------------------------
// Kernel 1: fused q/k/v 1x1 convs + fc (f_all).  (unchanged from R7)
// ---------------------------------------------------------------------------
__global__ __launch_bounds__(512) void qkvf_kernel(
    const float* __restrict__ x,
    const float* __restrict__ w1, const float* __restrict__ b1,
    const float* __restrict__ w2, const float* __restrict__ b2,
    const float* __restrict__ w3, const float* __restrict__ b3,
    const float* __restrict__ wfc,
    float* __restrict__ q, float* __restrict__ k, float* __restrict__ v,
    float* __restrict__ f)
{
    __shared__ float xs[64][128];       // [ci][l]            32 KB
    __shared__ float wlds[3][32][64];   // [mat][c_local][ci] 24 KB

    int bx    = blockIdx.x;
    int ltile = bx & 63;
    int half  = (bx >> 6) & 1;
    int b     = bx >> 7;
    int l0    = ltile * 128;
    int hdb   = half * 8;

    for (int t = threadIdx.x; t < 1536; t += 512) {
        int mat = t >> 9;
        int r   = t & 511;
        int cl  = r >> 4;
        int col = r & 15;
        int hh = cl >> 3, hdl = cl & 7;
        int c  = hh * 16 + hdb + hdl;
        const float* src = (mat == 0) ? w1 : (mat == 1) ? w2 : w3;
        ((float4*)wlds)[t] = ((const float4*)src)[c * 16 + col];
    }
    const float4* xg = (const float4*)(x + (size_t)b * 64 * 8192);
    for (int t = threadIdx.x; t < 2048; t += 512) {
        int ci = t >> 5, col = t & 31;
        ((float4*)xs)[t] = xg[ci * 2048 + (l0 >> 2) + col];
    }
    __syncthreads();

    int lane = threadIdx.x & 63;
    int wv   = __builtin_amdgcn_readfirstlane(threadIdx.x >> 6);
    int hd   = hdb + wv;
    int ll   = 2 * lane;

    float qa[4][2], ka[4][2], va[4][2];
#pragma unroll
    for (int hh = 0; hh < 4; ++hh) {
        int c = hh * 16 + hd;
        qa[hh][0] = qa[hh][1] = b1[c];
        ka[hh][0] = ka[hh][1] = b2[c];
        va[hh][0] = va[hh][1] = b3[c];
    }

#pragma unroll 4
    for (int c4 = 0; c4 < 16; ++c4) {
        float2 xv[4];
#pragma unroll
        for (int u = 0; u < 4; ++u)
            xv[u] = *(const float2*)&xs[c4 * 4 + u][ll];
#pragma unroll
        for (int hh = 0; hh < 4; ++hh) {
            int cl = hh * 8 + wv;
            float4 wq = *(const float4*)&wlds[0][cl][c4 * 4];
            float4 wk = *(const float4*)&wlds[1][cl][c4 * 4];
            float4 wx = *(const float4*)&wlds[2][cl][c4 * 4];
            qa[hh][0] = fmaf(wq.x, xv[0].x, qa[hh][0]);
            qa[hh][1] = fmaf(wq.x, xv[0].y, qa[hh][1]);
            qa[hh][0] = fmaf(wq.y, xv[1].x, qa[hh][0]);
            qa[hh][1] = fmaf(wq.y, xv[1].y, qa[hh][1]);
            qa[hh][0] = fmaf(wq.z, xv[2].x, qa[hh][0]);
            qa[hh][1] = fmaf(wq.z, xv[2].y, qa[hh][1]);
            qa[hh][0] = fmaf(wq.w, xv[3].x, qa[hh][0]);
            qa[hh][1] = fmaf(wq.w, xv[3].y, qa[hh][1]);

            ka[hh][0] = fmaf(wk.x, xv[0].x, ka[hh][0]);
            ka[hh][1] = fmaf(wk.x, xv[0].y, ka[hh][1]);
            ka[hh][0] = fmaf(wk.y, xv[1].x, ka[hh][0]);
            ka[hh][1] = fmaf(wk.y, xv[1].y, ka[hh][1]);
            ka[hh][0] = fmaf(wk.z, xv[2].x, ka[hh][0]);
            ka[hh][1] = fmaf(wk.z, xv[2].y, ka[hh][1]);
            ka[hh][0] = fmaf(wk.w, xv[3].x, ka[hh][0]);
            ka[hh][1] = fmaf(wk.w, xv[3].y, ka[hh][1]);

            va[hh][0] = fmaf(wx.x, xv[0].x, va[hh][0]);
            va[hh][1] = fmaf(wx.x, xv[0].y, va[hh][1]);
            va[hh][0] = fmaf(wx.y, xv[1].x, va[hh][0]);
            va[hh][1] = fmaf(wx.y, xv[1].y, va[hh][1]);
            va[hh][0] = fmaf(wx.z, xv[2].x, va[hh][0]);
            va[hh][1] = fmaf(wx.z, xv[2].y, va[hh][1]);
            va[hh][0] = fmaf(wx.w, xv[3].x, va[hh][0]);
            va[hh][1] = fmaf(wx.w, xv[3].y, va[hh][1]);
        }
    }

#pragma unroll
    for (int hh = 0; hh < 4; ++hh) {
        int c = hh * 16 + hd;
        size_t o = (size_t)(b * 64 + c) * 8192 + l0 + ll;
        *(float2*)&q[o] = make_float2(qa[hh][0] * 0.25f, qa[hh][1] * 0.25f);
        *(float2*)&k[o] = make_float2(ka[hh][0], ka[hh][1]);
        *(float2*)&v[o] = make_float2(va[hh][0], va[hh][1]);
    }

#pragma unroll
    for (int m = 0; m < 9; ++m) {
        float a0 = 0.f, a1 = 0.f;
#pragma unroll
        for (int hh = 0; hh < 4; ++hh) {
            a0 = fmaf(wfc[m * 12 + 0 + hh], qa[hh][0], a0);
            a1 = fmaf(wfc[m * 12 + 0 + hh], qa[hh][1], a1);
            a0 = fmaf(wfc[m * 12 + 4 + hh], ka[hh][0], a0);
            a1 = fmaf(wfc[m * 12 + 4 + hh], ka[hh][1], a1);
            a0 = fmaf(wfc[m * 12 + 8 + hh], va[hh][0], a0);
            a1 = fmaf(wfc[m * 12 + 8 + hh], va[hh][1], a1);
        }
        size_t o = ((size_t)(b * 9 + m) * 16 + hd) * 8192 + l0 + ll;
        *(float2*)&f[o] = make_float2(a0, a1);
    }
}

// ---------------------------------------------------------------------------
// Kernel 2: fused attention + conv, single writer of out.
// Block = (b, head, 16x16 tile), 512 thr, grid 256.
// ---------------------------------------------------------------------------
__global__ __launch_bounds__(512) void attconv_kernel(
    const float* __restrict__ q, const float* __restrict__ k,
    const float* __restrict__ v, const float* __restrict__ f,
    const float* __restrict__ wp, const float* __restrict__ bp,
    const float* __restrict__ wdep, const float* __restrict__ bdep,
    const float* __restrict__ rate1p, const float* __restrict__ rate2p,
    float* __restrict__ out)
{
    __shared__ float smem[20772];    // union: kp+vt (19360) | fs (36*577)
    __shared__ float att_buf[4096];  // [ch16][px256]  16 KB
    float* kp = smem;                // [22][22][20]
    float* vt = smem + 9680;

    int bx = blockIdx.x;          // 8 n * 4 yt * 8 xt = 256
    int xt = bx & 7;
    int yt = (bx >> 3) & 3;
    int n  = bx >> 5;
    int head = n & 3;
    int b    = n >> 2;
    int y0 = yt * 16, x0 = xt * 16;

    // ---------------- phase A: stage kp (= k - pe) and vt ----------------
    const int NELEM = 16 * 22 * 22;
    for (int e = threadIdx.x; e < NELEM; e += 512) {
        int tx  = e % 22;
        int rem = e / 22;
        int ty  = rem % 22;
        int c   = rem / 22;
        int sy = y0 + ty - 3; if (sy < 0) sy = -sy; else if (sy >= 64)  sy = 126 - sy;
        int sx = x0 + tx - 3; if (sx < 0) sx = -sx; else if (sx >= 128) sx = 254 - sx;
        int l = sy * 128 + sx;
        size_t o = (size_t)(b * 64 + head * 16 + c) * 8192 + l;
        int dd = l >> 10, r2 = l & 1023, ww = r2 >> 5, hh = r2 & 31;
        float ld = dd * (2.0f / 7.0f)  - 1.0f;
        float lw = ww * (2.0f / 31.0f) - 1.0f;
        float lh = hh * (2.0f / 31.0f) - 1.0f;
        float pe = bp[c];
        pe = fmaf(wp[c * 3 + 0], ld, pe);
        pe = fmaf(wp[c * 3 + 1], lw, pe);
        pe = fmaf(wp[c * 3 + 2], lh, pe);
        int li = (ty * 22 + tx) * 20 + c;
        kp[li] = k[o] - pe;
        vt[li] = v[o];
    }
    __syncthreads();

    // ---------------- phase B: attention ----------------
    {
        int pix  = threadIdx.x >> 1;
        int part = threadIdx.x & 1;
        int tx = pix & 15, ty = pix >> 4;
        int l = (y0 + ty) * 128 + (x0 + tx);
        int cb = part * 8;

        float qc[8];
#pragma unroll
        for (int c = 0; c < 8; ++c)
            qc[c] = q[(size_t)(b * 64 + head * 16 + cb + c) * 8192 + l];

        float lg[49];
#pragma unroll
        for (int i = 0; i < 7; ++i)
#pragma unroll
            for (int j = 0; j < 7; ++j) {
                const float4* p =
                    (const float4*)&kp[((ty + i) * 22 + tx + j) * 20 + cb];
                float4 a = p[0], b4 = p[1];
                float acc =      qc[0] * a.x;
                acc = fmaf(qc[1], a.y,  acc); acc = fmaf(qc[2], a.z,  acc);
                acc = fmaf(qc[3], a.w,  acc); acc = fmaf(qc[4], b4.x, acc);
                acc = fmaf(qc[5], b4.y, acc); acc = fmaf(qc[6], b4.z, acc);
                acc = fmaf(qc[7], b4.w, acc);
                lg[i * 7 + j] = acc;
            }
#pragma unroll
        for (int kk = 0; kk < 49; ++kk)
            lg[kk] += __shfl_xor(lg[kk], 1, 64);

        float mx = lg[0];
#pragma unroll
        for (int kk = 1; kk < 49; ++kk) mx = fmaxf(mx, lg[kk]);
        float se = 0.f;
#pragma unroll
        for (int kk = 0; kk < 49; ++kk) { lg[kk] = __expf(lg[kk] - mx); se += lg[kk]; }
        float scale = rate1p[0] / se;

        float oc[8];
#pragma unroll
        for (int c = 0; c < 8; ++c) oc[c] = 0.f;
#pragma unroll
        for (int i = 0; i < 7; ++i)
#pragma unroll
            for (int j = 0; j < 7; ++j) {
                float wgt = lg[i * 7 + j];
                const float4* p =
                    (const float4*)&vt[((ty + i) * 22 + tx + j) * 20 + cb];
                float4 a = p[0], b4 = p[1];
                oc[0] = fmaf(wgt, a.x,  oc[0]); oc[1] = fmaf(wgt, a.y,  oc[1]);
                oc[2] = fmaf(wgt, a.z,  oc[2]); oc[3] = fmaf(wgt, a.w,  oc[3]);
                oc[4] = fmaf(wgt, b4.x, oc[4]); oc[5] = fmaf(wgt, b4.y, oc[5]);
                oc[6] = fmaf(wgt, b4.z, oc[6]); oc[7] = fmaf(wgt, b4.w, oc[7]);
            }

        // park att result; nothing from phase A/B stays live past here
#pragma unroll
        for (int c = 0; c < 8; ++c)
            att_buf[(cb + c) * 256 + pix] = oc[c] * scale;
    }
    __syncthreads();   // kp/vt reads + att_buf writes complete

    // ---------------- phase C staging: f halo ----------------
    // fs[c36][y2r(4)][s(8)][xo(18)], slab padded 576->577 (bank decorrelate)
    float* fs = smem;
    const float* fb = f + (size_t)(b * 144 + 36 * head) * 8192;
    int y2base = (y0 >> 3) - 1;
    for (int e = threadIdx.x; e < 20736; e += 512) {
        int c36 = e / 576;
        int rem = e % 576;
        int xo  = rem % 18;
        int r   = rem / 18;
        int s   = r & 7;
        int y2r = r >> 3;
        int y2  = y2base + y2r;
        int x2  = s * 128 + x0 - 1 + xo;
        float val = 0.f;
        if (y2 >= 0 && y2 < 8 && x2 >= 0 && x2 < 1024)
            val = fb[(size_t)c36 * 8192 + y2 * 1024 + x2];
        fs[c36 * 577 + rem] = val;
    }
    __syncthreads();

    // ---------------- phase C: conv, wave-uniform channels ----------------
    int wv   = __builtin_amdgcn_readfirstlane(threadIdx.x >> 6); // 0..7
    int g    = wv >> 1;            // f group (local): channels share taps
    int ch0  = 2 * wv;             // local out-channel base
    int lane = threadIdx.x & 63;
    int txc  = lane & 15;
    int qq   = lane >> 4;          // strip quarter

    float cacc[2][2][2];           // [ss][yl2][cc]
#pragma unroll
    for (int a0 = 0; a0 < 2; ++a0)
#pragma unroll
        for (int a1 = 0; a1 < 2; ++a1)
#pragma unroll
            for (int a2 = 0; a2 < 2; ++a2) cacc[a0][a1][a2] = 0.f;

    for (int i = 0; i < 9; ++i) {
        const float* fsl = &fs[(g * 9 + i) * 577];
        float w0[9], w1[9];
#pragma unroll
        for (int t = 0; t < 9; ++t) {
            w0[t] = wdep[((head * 16 + ch0)     * 9 + i) * 9 + t];
            w1[t] = wdep[((head * 16 + ch0 + 1) * 9 + i) * 9 + t];
        }
#pragma unroll
        for (int ss = 0; ss < 2; ++ss) {
            int sl = qq + 4 * ss;
            float fr[4][3];
#pragma unroll
            for (int r = 0; r < 4; ++r)
#pragma unroll
                for (int kx = 0; kx < 3; ++kx)
                    fr[r][kx] = fsl[(r * 8 + sl) * 18 + txc + kx];
#pragma unroll
            for (int yl2 = 0; yl2 < 2; ++yl2)
#pragma unroll
                for (int ky = 0; ky < 3; ++ky)
#pragma unroll
                    for (int kx = 0; kx < 3; ++kx) {
                        float fv = fr[yl2 + ky][kx];
                        cacc[ss][yl2][0] = fmaf(w0[ky * 3 + kx], fv, cacc[ss][yl2][0]);
                        cacc[ss][yl2][1] = fmaf(w1[ky * 3 + kx], fv, cacc[ss][yl2][1]);
                    }
        }
    }

    float rate2 = rate2p[0];
    float bd0 = bdep[head * 16 + ch0];
    float bd1 = bdep[head * 16 + ch0 + 1];
#pragma unroll
    for (int ss = 0; ss < 2; ++ss)
#pragma unroll
        for (int yl2 = 0; yl2 < 2; ++yl2) {
            int ty = yl2 * 8 + qq + 4 * ss;
            int p  = ty * 16 + txc;
            size_t base = (size_t)(b * 64 + head * 16 + ch0) * 8192
                          + (y0 + ty) * 128 + x0 + txc;
            out[base] = att_buf[ch0 * 256 + p]
                        + rate2 * (cacc[ss][yl2][0] + bd0);
            out[base + 8192] = att_buf[(ch0 + 1) * 256 + p]
                               + rate2 * (cacc[ss][yl2][1] + bd1);
        }
}

// ---------------------------------------------------------------------------
extern "C" void kernel_launch(void* const* d_in, const int* in_sizes, int n_in,
                              void* d_out, int out_size, void* d_ws, size_t ws_size,
                              hipStream_t stream)
{
    (void)in_sizes; (void)n_in; (void)out_size; (void)ws_size;
    const float* x     = (const float*)d_in[0];
    const float* w1    = (const float*)d_in[1];
    const float* b1    = (const float*)d_in[2];
    const float* w2    = (const float*)d_in[3];
    const float* b2    = (const float*)d_in[4];
    const float* w3    = (const float*)d_in[5];
    const float* b3    = (const float*)d_in[6];
    const float* wp    = (const float*)d_in[7];
    const float* bp    = (const float*)d_in[8];
    const float* wfc   = (const float*)d_in[9];
    const float* wdep  = (const float*)d_in[10];
    const float* bdep  = (const float*)d_in[11];
    const float* rate1 = (const float*)d_in[12];
    const float* rate2 = (const float*)d_in[13];
    float* out = (float*)d_out;

    float* wsf = (float*)d_ws;
    float* q = wsf;                 // 3 x 1,048,576 floats (q,k,v)
    float* k = wsf + 1048576;
    float* v = wsf + 2097152;
    float* f = wsf + 3145728;       // 2,359,296 floats

    qkvf_kernel  <<<256, 512, 0, stream>>>(x, w1, b1, w2, b2, w3, b3, wfc,
                                           q, k, v, f);
    attconv_kernel<<<256, 512, 0, stream>>>(q, k, v, f, wp, bp, wdep, bdep,
                                            rate1, rate2, out);
}

// Round 9
// 118.938 us; speedup vs baseline: 1.0688x; 1.0688x over previous
//
#include <hip/hip_runtime.h>
#include <hip/hip_fp16.h>

// ACmix: b=2, C=64 (HEAD=4 x HEAD_DIM=16), (d,w,h)=(8,32,32), L=8192
// Attention view: (H2,W2)=(64,128). Conv view: (8, 1024). K_ATT=7 PAD=3.
//
// R9 = R7 structure (3 dispatches; R8 fusion reverted: 1 block/CU + 4
// barriers serialize, inter-kernel overlap wins) + att LDS in packed f16:
// kp/vt stored as __half2 (12 dw/pixel stride, b128-aligned, conflict-free)
// -> att's ds_read_b128 count halves (196 -> 98 per thread).

static __device__ __forceinline__ float2 h2f2(float w) {
    __half2 h = *reinterpret_cast<__half2*>(&w);
    return __half22float2(h);
}

// ---------------------------------------------------------------------------
// Kernel 1: fused q/k/v 1x1 convs + fc (f_all).  (unchanged from R7)
// ---------------------------------------------------------------------------
__global__ __launch_bounds__(512) void qkvf_kernel(
    const float* __restrict__ x,
    const float* __restrict__ w1, const float* __restrict__ b1,
    const float* __restrict__ w2, const float* __restrict__ b2,
    const float* __restrict__ w3, const float* __restrict__ b3,
    const float* __restrict__ wfc,
    float* __restrict__ q, float* __restrict__ k, float* __restrict__ v,
    float* __restrict__ f)
{
    __shared__ float xs[64][128];       // [ci][l]            32 KB
    __shared__ float wlds[3][32][64];   // [mat][c_local][ci] 24 KB

    int bx    = blockIdx.x;
    int ltile = bx & 63;
    int half  = (bx >> 6) & 1;
    int b     = bx >> 7;
    int l0    = ltile * 128;
    int hdb   = half * 8;

    for (int t = threadIdx.x; t < 1536; t += 512) {
        int mat = t >> 9;
        int r   = t & 511;
        int cl  = r >> 4;
        int col = r & 15;
        int hh = cl >> 3, hdl = cl & 7;
        int c  = hh * 16 + hdb + hdl;
        const float* src = (mat == 0) ? w1 : (mat == 1) ? w2 : w3;
        ((float4*)wlds)[t] = ((const float4*)src)[c * 16 + col];
    }
    const float4* xg = (const float4*)(x + (size_t)b * 64 * 8192);
    for (int t = threadIdx.x; t < 2048; t += 512) {
        int ci = t >> 5, col = t & 31;
        ((float4*)xs)[t] = xg[ci * 2048 + (l0 >> 2) + col];
    }
    __syncthreads();

    int lane = threadIdx.x & 63;
    int wv   = __builtin_amdgcn_readfirstlane(threadIdx.x >> 6);
    int hd   = hdb + wv;
    int ll   = 2 * lane;

    float qa[4][2], ka[4][2], va[4][2];
#pragma unroll
    for (int hh = 0; hh < 4; ++hh) {
        int c = hh * 16 + hd;
        qa[hh][0] = qa[hh][1] = b1[c];
        ka[hh][0] = ka[hh][1] = b2[c];
        va[hh][0] = va[hh][1] = b3[c];
    }

#pragma unroll 4
    for (int c4 = 0; c4 < 16; ++c4) {
        float2 xv[4];
#pragma unroll
        for (int u = 0; u < 4; ++u)
            xv[u] = *(const float2*)&xs[c4 * 4 + u][ll];
#pragma unroll
        for (int hh = 0; hh < 4; ++hh) {
            int cl = hh * 8 + wv;
            float4 wq = *(const float4*)&wlds[0][cl][c4 * 4];
            float4 wk = *(const float4*)&wlds[1][cl][c4 * 4];
            float4 wx = *(const float4*)&wlds[2][cl][c4 * 4];
            qa[hh][0] = fmaf(wq.x, xv[0].x, qa[hh][0]);
            qa[hh][1] = fmaf(wq.x, xv[0].y, qa[hh][1]);
            qa[hh][0] = fmaf(wq.y, xv[1].x, qa[hh][0]);
            qa[hh][1] = fmaf(wq.y, xv[1].y, qa[hh][1]);
            qa[hh][0] = fmaf(wq.z, xv[2].x, qa[hh][0]);
            qa[hh][1] = fmaf(wq.z, xv[2].y, qa[hh][1]);
            qa[hh][0] = fmaf(wq.w, xv[3].x, qa[hh][0]);
            qa[hh][1] = fmaf(wq.w, xv[3].y, qa[hh][1]);

            ka[hh][0] = fmaf(wk.x, xv[0].x, ka[hh][0]);
            ka[hh][1] = fmaf(wk.x, xv[0].y, ka[hh][1]);
            ka[hh][0] = fmaf(wk.y, xv[1].x, ka[hh][0]);
            ka[hh][1] = fmaf(wk.y, xv[1].y, ka[hh][1]);
            ka[hh][0] = fmaf(wk.z, xv[2].x, ka[hh][0]);
            ka[hh][1] = fmaf(wk.z, xv[2].y, ka[hh][1]);
            ka[hh][0] = fmaf(wk.w, xv[3].x, ka[hh][0]);
            ka[hh][1] = fmaf(wk.w, xv[3].y, ka[hh][1]);

            va[hh][0] = fmaf(wx.x, xv[0].x, va[hh][0]);
            va[hh][1] = fmaf(wx.x, xv[0].y, va[hh][1]);
            va[hh][0] = fmaf(wx.y, xv[1].x, va[hh][0]);
            va[hh][1] = fmaf(wx.y, xv[1].y, va[hh][1]);
            va[hh][0] = fmaf(wx.z, xv[2].x, va[hh][0]);
            va[hh][1] = fmaf(wx.z, xv[2].y, va[hh][1]);
            va[hh][0] = fmaf(wx.w, xv[3].x, va[hh][0]);
            va[hh][1] = fmaf(wx.w, xv[3].y, va[hh][1]);
        }
    }

#pragma unroll
    for (int hh = 0; hh < 4; ++hh) {
        int c = hh * 16 + hd;
        size_t o = (size_t)(b * 64 + c) * 8192 + l0 + ll;
        *(float2*)&q[o] = make_float2(qa[hh][0] * 0.25f, qa[hh][1] * 0.25f);
        *(float2*)&k[o] = make_float2(ka[hh][0], ka[hh][1]);
        *(float2*)&v[o] = make_float2(va[hh][0], va[hh][1]);
    }

#pragma unroll
    for (int m = 0; m < 9; ++m) {
        float a0 = 0.f, a1 = 0.f;
#pragma unroll
        for (int hh = 0; hh < 4; ++hh) {
            a0 = fmaf(wfc[m * 12 + 0 + hh], qa[hh][0], a0);
            a1 = fmaf(wfc[m * 12 + 0 + hh], qa[hh][1], a1);
            a0 = fmaf(wfc[m * 12 + 4 + hh], ka[hh][0], a0);
            a1 = fmaf(wfc[m * 12 + 4 + hh], ka[hh][1], a1);
            a0 = fmaf(wfc[m * 12 + 8 + hh], va[hh][0], a0);
            a1 = fmaf(wfc[m * 12 + 8 + hh], va[hh][1], a1);
        }
        size_t o = ((size_t)(b * 9 + m) * 16 + hd) * 8192 + l0 + ll;
        *(float2*)&f[o] = make_float2(a0, a1);
    }
}

// ---------------------------------------------------------------------------
// Kernel 2: attention branch.  out = rate1 * out_att.
// f16-packed LDS: kp/vt as __half2, pixel stride 12 dwords (b128-aligned,
// starts 12t%32 tile 8 disjoint 4-bank groups -> conflict-free minimum).
// Staging: thread packs channels {2c2, 2c2+1} of one halo pixel (b32 write,
// 2 lanes/bank = free).  Compute: 1 b128 per window per matrix per thread.
// ---------------------------------------------------------------------------
__global__ __launch_bounds__(512, 4) void att_kernel(
    const float* __restrict__ q, const float* __restrict__ k,
    const float* __restrict__ v,
    const float* __restrict__ wp, const float* __restrict__ bp,
    const float* __restrict__ rate1p, float* __restrict__ out)
{
    __shared__ float kpb[484 * 12];   // 23.2 KB (f16x2 packed)
    __shared__ float vtb[484 * 12];   // 23.2 KB

    int bx = blockIdx.x;          // 8 n * 4 yt * 8 xt = 256
    int xt = bx & 7;
    int yt = (bx >> 3) & 3;
    int n  = bx >> 5;
    int head = n & 3;
    int b    = n >> 2;
    int y0 = yt * 16, x0 = xt * 16;

    // ---- stage: e = px(484) x c2(8); thread handles channel pair ----
    for (int e = threadIdx.x; e < 3872; e += 512) {
        int c2 = e & 7;
        int px = e >> 3;
        int ty = px / 22, tx = px % 22;
        int c0 = c2 * 2;
        int sy = y0 + ty - 3; if (sy < 0) sy = -sy; else if (sy >= 64)  sy = 126 - sy;
        int sx = x0 + tx - 3; if (sx < 0) sx = -sx; else if (sx >= 128) sx = 254 - sx;
        int l = sy * 128 + sx;
        size_t o = (size_t)(b * 64 + head * 16 + c0) * 8192 + l;
        float k0 = k[o], k1 = k[o + 8192];
        float v0 = v[o], v1 = v[o + 8192];
        int dd = l >> 10, r2 = l & 1023, ww = r2 >> 5, hh2 = r2 & 31;
        float ld = dd  * (2.0f / 7.0f)  - 1.0f;
        float lw = ww  * (2.0f / 31.0f) - 1.0f;
        float lh = hh2 * (2.0f / 31.0f) - 1.0f;
        float pe0 = bp[c0];
        pe0 = fmaf(wp[c0 * 3 + 0], ld, pe0);
        pe0 = fmaf(wp[c0 * 3 + 1], lw, pe0);
        pe0 = fmaf(wp[c0 * 3 + 2], lh, pe0);
        float pe1 = bp[c0 + 1];
        pe1 = fmaf(wp[c0 * 3 + 3], ld, pe1);
        pe1 = fmaf(wp[c0 * 3 + 4], lw, pe1);
        pe1 = fmaf(wp[c0 * 3 + 5], lh, pe1);
        __half2 hk = __floats2half2_rn(k0 - pe0, k1 - pe1);
        __half2 hv = __floats2half2_rn(v0, v1);
        kpb[px * 12 + c2] = *reinterpret_cast<float*>(&hk);
        vtb[px * 12 + c2] = *reinterpret_cast<float*>(&hv);
    }
    __syncthreads();

    int pix  = threadIdx.x >> 1;      // 0..255
    int part = threadIdx.x & 1;       // channel half
    int tx = pix & 15, ty = pix >> 4;
    int l = (y0 + ty) * 128 + (x0 + tx);
    int cb = part * 8;                // channel base

    float qc[8];
#pragma unroll
    for (int c = 0; c < 8; ++c)
        qc[c] = q[(size_t)(b * 64 + head * 16 + cb + c) * 8192 + l]; // pre-scaled

    float lg[49];
#pragma unroll
    for (int i = 0; i < 7; ++i)
#pragma unroll
        for (int j = 0; j < 7; ++j) {
            float4 r = *(const float4*)&kpb[((ty + i) * 22 + tx + j) * 12
                                            + part * 4];
            float2 u0 = h2f2(r.x), u1 = h2f2(r.y),
                   u2 = h2f2(r.z), u3 = h2f2(r.w);
            float acc =      qc[0] * u0.x;
            acc = fmaf(qc[1], u0.y, acc); acc = fmaf(qc[2], u1.x, acc);
            acc = fmaf(qc[3], u1.y, acc); acc = fmaf(qc[4], u2.x, acc);
            acc = fmaf(qc[5], u2.y, acc); acc = fmaf(qc[6], u3.x, acc);
            acc = fmaf(qc[7], u3.y, acc);
            lg[i * 7 + j] = acc;
        }
#pragma unroll
    for (int kk = 0; kk < 49; ++kk)
        lg[kk] += __shfl_xor(lg[kk], 1, 64);

    float mx = lg[0];
#pragma unroll
    for (int kk = 1; kk < 49; ++kk) mx = fmaxf(mx, lg[kk]);
    float se = 0.f;
#pragma unroll
    for (int kk = 0; kk < 49; ++kk) { lg[kk] = __expf(lg[kk] - mx); se += lg[kk]; }
    float scale = rate1p[0] / se;

    float oc[8];
#pragma unroll
    for (int c = 0; c < 8; ++c) oc[c] = 0.f;
#pragma unroll
    for (int i = 0; i < 7; ++i)
#pragma unroll
        for (int j = 0; j < 7; ++j) {
            float wgt = lg[i * 7 + j];
            float4 r = *(const float4*)&vtb[((ty + i) * 22 + tx + j) * 12
                                            + part * 4];
            float2 u0 = h2f2(r.x), u1 = h2f2(r.y),
                   u2 = h2f2(r.z), u3 = h2f2(r.w);
            oc[0] = fmaf(wgt, u0.x, oc[0]); oc[1] = fmaf(wgt, u0.y, oc[1]);
            oc[2] = fmaf(wgt, u1.x, oc[2]); oc[3] = fmaf(wgt, u1.y, oc[3]);
            oc[4] = fmaf(wgt, u2.x, oc[4]); oc[5] = fmaf(wgt, u2.y, oc[5]);
            oc[6] = fmaf(wgt, u3.x, oc[6]); oc[7] = fmaf(wgt, u3.y, oc[7]);
        }

#pragma unroll
    for (int c = 0; c < 8; ++c)
        out[(size_t)(b * 64 + head * 16 + cb + c) * 8192 + l] = oc[c] * scale;
}

// ---------------------------------------------------------------------------
// Kernel 3: conv branch + combine.  (unchanged from R7)
// 512 blocks (64-wide x-tiles, ft 19 KB) -> 2 blocks/CU, 8 waves/CU.
// ---------------------------------------------------------------------------
__global__ __launch_bounds__(256) void conv_kernel(
    const float* __restrict__ f,
    const float* __restrict__ wdep, const float* __restrict__ bdep,
    const float* __restrict__ rate2p, float* __restrict__ out)
{
    __shared__ float ft[9][8][66];

    int bx = blockIdx.x;          // 2 b * 16 g * 16 xt = 512
    int xt = bx & 15;
    int g  = (bx >> 4) & 15;
    int b  = bx >> 8;
    int x0 = xt * 64;

    const int NE = 9 * 8 * 66;    // 4752
    for (int e = threadIdx.x; e < NE; e += 256) {
        int xx  = e % 66;
        int rem = e / 66;
        int y = rem % 8, i = rem / 8;
        int gx = x0 + xx - 1;
        float val = 0.f;
        if (gx >= 0 && gx < 1024) {
            int c144 = g * 9 + i;
            val = f[((size_t)(b * 144 + c144)) * 8192 + y * 1024 + gx];
        }
        ft[i][y][xx] = val;
    }
    __syncthreads();

    int xl = threadIdx.x & 63;
    int op = __builtin_amdgcn_readfirstlane(threadIdx.x >> 6); // wave id 0..3
    int o  = g * 4 + op;
    float rate2 = rate2p[0];

    float acc[8];
#pragma unroll
    for (int y = 0; y < 8; ++y) acc[y] = 0.f;

    for (int i = 0; i < 9; ++i) {
        float fr[10][3];
#pragma unroll
        for (int dx = 0; dx < 3; ++dx) { fr[0][dx] = 0.f; fr[9][dx] = 0.f; }
#pragma unroll
        for (int y = 0; y < 8; ++y)
#pragma unroll
            for (int dx = 0; dx < 3; ++dx)
                fr[y + 1][dx] = ft[i][y][xl + dx];
#pragma unroll
        for (int ky = 0; ky < 3; ++ky)
#pragma unroll
            for (int kx = 0; kx < 3; ++kx) {
                float wvv = wdep[((o * 9 + i) * 3 + ky) * 3 + kx];
#pragma unroll
                for (int y = 0; y < 8; ++y)
                    acc[y] = fmaf(wvv, fr[y + ky][kx], acc[y]);
            }
    }

    float bd = bdep[o];
#pragma unroll
    for (int y = 0; y < 8; ++y) {
        size_t idx = (size_t)(b * 64 + o) * 8192 + y * 1024 + x0 + xl;
        out[idx] = out[idx] + rate2 * (acc[y] + bd);
    }
}

// ---------------------------------------------------------------------------
extern "C" void kernel_launch(void* const* d_in, const int* in_sizes, int n_in,
                              void* d_out, int out_size, void* d_ws, size_t ws_size,
                              hipStream_t stream)
{
    (void)in_sizes; (void)n_in; (void)out_size; (void)ws_size;
    const float* x     = (const float*)d_in[0];
    const float* w1    = (const float*)d_in[1];
    const float* b1    = (const float*)d_in[2];
    const float* w2    = (const float*)d_in[3];
    const float* b2    = (const float*)d_in[4];
    const float* w3    = (const float*)d_in[5];
    const float* b3    = (const float*)d_in[6];
    const float* wp    = (const float*)d_in[7];
    const float* bp    = (const float*)d_in[8];
    const float* wfc   = (const float*)d_in[9];
    const float* wdep  = (const float*)d_in[10];
    const float* bdep  = (const float*)d_in[11];
    const float* rate1 = (const float*)d_in[12];
    const float* rate2 = (const float*)d_in[13];
    float* out = (float*)d_out;

    float* wsf = (float*)d_ws;
    float* q = wsf;                 // 3 x 1,048,576 floats (q,k,v)
    float* k = wsf + 1048576;
    float* v = wsf + 2097152;
    float* f = wsf + 3145728;       // 2,359,296 floats

    qkvf_kernel<<<256, 512, 0, stream>>>(x, w1, b1, w2, b2, w3, b3, wfc,
                                         q, k, v, f);
    att_kernel <<<256, 512, 0, stream>>>(q, k, v, wp, bp, rate1, out);
    conv_kernel<<<512, 256, 0, stream>>>(f, wdep, bdep, rate2, out);
}